// Round 1
// baseline (748.538 us; speedup 1.0000x reference)
//
#include <hip/hip_runtime.h>

// Problem constants (match the JAX reference)
#define MAXVAL   5843
#define TOP_K    200
#define STEP_SZ  30
#define N_STEPS  189      // ceil((5843-200)/30)
#define BATCH    4

// One 64-lane wave per row. The row's surviving window is the 200 contiguous
// columns [start, start+200) with start = min(q,188)*30. Masked entries of the
// reference softmax are exp(-1e7 - max)/sum which underflows to exactly 0.0f
// in fp32, so zero-fill (done by hipMemsetAsync before this kernel) is exact.
__global__ __launch_bounds__(256) void window_softmax_kernel(
        const float* __restrict__ X, float* __restrict__ Out) {
    const int gtid  = blockIdx.x * blockDim.x + threadIdx.x;
    const int wave  = gtid >> 6;          // global wave id == row id
    const int lane  = gtid & 63;
    const int nrows = BATCH * MAXVAL;
    if (wave >= nrows) return;

    const int q     = wave % MAXVAL;                       // query index within matrix
    const int start = (q < N_STEPS - 1 ? q : N_STEPS - 1) * STEP_SZ;

    const size_t row_off = (size_t)wave * MAXVAL + start;
    const float* xrow = X + row_off;

    // Load up to 4 window elements per lane (200 = 3*64 + 8)
    float v[4];
    float m = -1e30f;
#pragma unroll
    for (int k = 0; k < 4; ++k) {
        const int idx = lane + 64 * k;
        v[k] = (idx < TOP_K) ? xrow[idx] : -1e30f;
        m = fmaxf(m, v[k]);
    }
    // Wave-wide max (64 lanes)
#pragma unroll
    for (int off = 32; off > 0; off >>= 1)
        m = fmaxf(m, __shfl_xor(m, off, 64));

    // exp and wave-wide sum
    float s = 0.0f;
#pragma unroll
    for (int k = 0; k < 4; ++k) {
        const int idx = lane + 64 * k;
        v[k] = (idx < TOP_K) ? __expf(v[k] - m) : 0.0f;
        s += v[k];
    }
#pragma unroll
    for (int off = 32; off > 0; off >>= 1)
        s += __shfl_xor(s, off, 64);

    const float inv = 1.0f / s;

    float* orow = Out + row_off;
#pragma unroll
    for (int k = 0; k < 4; ++k) {
        const int idx = lane + 64 * k;
        if (idx < TOP_K) orow[idx] = v[k] * inv;
    }
}

extern "C" void kernel_launch(void* const* d_in, const int* in_sizes, int n_in,
                              void* d_out, int out_size, void* d_ws, size_t ws_size,
                              hipStream_t stream) {
    const float* X = (const float*)d_in[0];
    float* out = (float*)d_out;

    // 1) Zero the whole output (masked positions are exactly 0.0f in fp32).
    hipMemsetAsync(d_out, 0, (size_t)out_size * sizeof(float), stream);

    // 2) Softmax over each row's 200-wide window; one wave per row.
    const int nrows = BATCH * MAXVAL;            // 23372
    const int waves_per_block = 4;               // 256 threads
    const int blocks = (nrows + waves_per_block - 1) / waves_per_block;
    window_softmax_kernel<<<blocks, 256, 0, stream>>>(X, out);
}